// Round 2
// baseline (326.583 us; speedup 1.0000x reference)
//
#include <hip/hip_runtime.h>

#define NSEQ 2048
#define DH 64
#define NH 16
#define BQ 64
#define BKV 64
#define LP 72   // LDS row stride in bf16 elems (padded vs 64 to break bank conflicts)
#define PART_STRIDE 4224  // 64*64 acc + 64 m + 64 l floats per partial

typedef __attribute__((ext_vector_type(8))) short bf16x8;
typedef __attribute__((ext_vector_type(4))) float f32x4;

static __device__ __forceinline__ short f2bf(float f) {
    unsigned u = __float_as_uint(f);
    u += 0x7fffu + ((u >> 16) & 1u);   // round-to-nearest-even
    return (short)(u >> 16);
}

// ---------------- gating ----------------
__global__ void gate_partial(const float* __restrict__ gi, float* __restrict__ wsA) {
    int b = blockIdx.x >> 3, sl = blockIdx.x & 7;
    int tid = threadIdx.x;
    int g = tid & 127, half = tid >> 7;
    float s = 0.f;
    int n0 = sl * 256;
    for (int n = n0 + half; n < n0 + 256; n += 2)
        s += gi[((size_t)b * NSEQ + n) * 128 + g];
    __shared__ float part[2][128];
    part[half][g] = s;
    __syncthreads();
    if (tid < 128) wsA[(b * 8 + sl) * 128 + tid] = part[0][tid] + part[1][tid];
}

__global__ void gate_final(const float* __restrict__ wsA, const float* __restrict__ Wg,
                           const float* __restrict__ bg, float* __restrict__ ws_sm,
                           int* __restrict__ ws_idx) {
    int b = blockIdx.x, tid = threadIdx.x;
    __shared__ float meanv[128];
    __shared__ float logits[NH];
    if (tid < 128) {
        float s = 0.f;
        for (int sl = 0; sl < 8; ++sl) s += wsA[(b * 8 + sl) * 128 + tid];
        meanv[tid] = s * (1.0f / NSEQ);
    }
    __syncthreads();
    if (tid < 128) {
        int h = tid >> 3, j = tid & 7;
        float p = 0.f;
        for (int i = 0; i < 16; ++i) { int g = j + 8 * i; p += meanv[g] * Wg[h * 128 + g]; }
        p += __shfl_xor(p, 1);
        p += __shfl_xor(p, 2);
        p += __shfl_xor(p, 4);
        if (j == 0) logits[h] = p + bg[h];
    }
    __syncthreads();
    if (tid == 0) {
        float mx = logits[0];
        for (int h = 1; h < NH; ++h) mx = fmaxf(mx, logits[h]);
        float e[NH], sum = 0.f;
        for (int h = 0; h < NH; ++h) { e[h] = __expf(logits[h] - mx); sum += e[h]; }
        float inv = 1.0f / sum;
        for (int h = 0; h < NH; ++h) ws_sm[b * NH + h] = e[h] * inv;
        int i1 = 0;
        for (int h = 1; h < NH; ++h) if (logits[h] > logits[i1]) i1 = h;
        int i2 = (i1 == 0) ? 1 : 0;
        for (int h = 0; h < NH; ++h) if (h != i1 && logits[h] > logits[i2]) i2 = h;
        ws_idx[b * 2 + 0] = i1;
        ws_idx[b * 2 + 1] = i2;
    }
}

__global__ void lb_kernel(const float* __restrict__ ws_sm, const int* __restrict__ ws_idx,
                          float* __restrict__ out_lb) {
    if (threadIdx.x == 0 && blockIdx.x == 0) {
        float counts[NH];
        for (int h = 0; h < NH; ++h) counts[h] = 0.f;
        for (int i = 0; i < 16; ++i) counts[ws_idx[i]] += 1.0f;
        float lb = 0.f;
        for (int h = 0; h < NH; ++h) {
            float msm = 0.f;
            for (int b = 0; b < 8; ++b) msm += ws_sm[b * NH + h];
            msm *= (1.0f / 8.0f);
            lb += msm * (counts[h] / (16.0f + 1e-6f));
        }
        out_lb[0] = lb * (float)NH;
    }
}

// ---------------- attention (flash-decoding: KV split across blocks) ----------------
__global__ __launch_bounds__(256, 5)
void attn_kernel(const float* __restrict__ q, const float* __restrict__ k,
                 const float* __restrict__ v, const float* __restrict__ mask,
                 const int* __restrict__ topk, float* __restrict__ out,
                 float* __restrict__ part, int SPLIT) {
    const int qt = blockIdx.x & 31;   // q-tile 0..31
    const int sp = blockIdx.x >> 5;   // kv-split index 0..SPLIT-1
    const int kk = blockIdx.y;        // 0..1
    const int b  = blockIdx.z;        // 0..7
    const int h  = topk[b * 2 + kk];
    const int tid = threadIdx.x;
    const int wave = tid >> 6;
    const int lane = tid & 63;
    const int lr = lane & 15;    // row-in-16 (A) / col (B, C/D)
    const int lg = lane >> 4;    // k-chunk group 0..3

    const int nt = 32 / SPLIT;            // KV tiles this block handles
    const int t_begin = sp * nt;          // first tile index

    __shared__ short Kb[BKV][LP];     // K tile, bf16 row-major [n][d]
    __shared__ short Vt[DH][LP];      // V tile transposed, [d][n]
    __shared__ short Pl[4][16][LP];   // per-wave P tile [qrow16][n64]

    const float QSC = 0.125f * 1.4426950408889634f; // 1/sqrt(64) * log2(e)
    const float MSC = 1.4426950408889634f;          // log2(e) for the mask add

    const size_t headoff = ((size_t)b * NH + h) * (size_t)NSEQ * DH;

    // Q fragments: lane holds q[row=lr][d = f*32 + lg*8 + j], scaled
    bf16x8 qf[2];
    {
        const float* qp = q + headoff + (size_t)(qt * BQ + wave * 16 + lr) * DH;
        #pragma unroll
        for (int f = 0; f < 2; ++f) {
            const float* p = qp + f * 32 + lg * 8;
            float4 a = *(const float4*)p;
            float4 c = *(const float4*)(p + 4);
            qf[f][0] = f2bf(a.x * QSC); qf[f][1] = f2bf(a.y * QSC);
            qf[f][2] = f2bf(a.z * QSC); qf[f][3] = f2bf(a.w * QSC);
            qf[f][4] = f2bf(c.x * QSC); qf[f][5] = f2bf(c.y * QSC);
            qf[f][6] = f2bf(c.z * QSC); qf[f][7] = f2bf(c.w * QSC);
        }
    }

    f32x4 acc[4];
    float m_r[4], l_r[4];
    #pragma unroll
    for (int dt = 0; dt < 4; ++dt)
        for (int r = 0; r < 4; ++r) acc[dt][r] = 0.f;
    #pragma unroll
    for (int r = 0; r < 4; ++r) { m_r[r] = -INFINITY; l_r[r] = 0.f; }

    const float* kb = k + headoff;
    const float* vb = v + headoff;
    const float* mb = mask + (size_t)b * NSEQ * NSEQ + (size_t)(qt * BQ + wave * 16) * NSEQ;

    const int srow = tid >> 4;        // staging row 0..15
    const int scol = (tid & 15) * 4;  // staging col 0,4..60

    float mA[16], mB[16];
    // prologue: load mask for the first tile into mA
    {
        const int t0 = t_begin * BKV;
        #pragma unroll
        for (int r = 0; r < 4; ++r) {
            const float* mp = mb + (size_t)(4 * lg + r) * NSEQ + t0 + lr;
            #pragma unroll
            for (int ct = 0; ct < 4; ++ct) mA[r * 4 + ct] = mp[ct * 16];
        }
    }

#define ATTN_STEP(MU, MP, tloc) do {                                                  \
    const int t0 = (t_begin + (tloc)) * BKV;                                          \
    __syncthreads();                                                                  \
    _Pragma("unroll")                                                                 \
    for (int pp = 0; pp < 4; ++pp) {                                                  \
        int n = pp * 16 + srow;                                                       \
        float4 k4 = *(const float4*)(kb + (size_t)(t0 + n) * DH + scol);              \
        *(short4*)&Kb[n][scol] = make_short4(f2bf(k4.x), f2bf(k4.y), f2bf(k4.z), f2bf(k4.w)); \
        float4 v4 = *(const float4*)(vb + (size_t)(t0 + n) * DH + scol);              \
        Vt[scol + 0][n] = f2bf(v4.x);                                                 \
        Vt[scol + 1][n] = f2bf(v4.y);                                                 \
        Vt[scol + 2][n] = f2bf(v4.z);                                                 \
        Vt[scol + 3][n] = f2bf(v4.w);                                                 \
    }                                                                                 \
    __syncthreads();                                                                  \
    f32x4 s[4];                                                                       \
    _Pragma("unroll")                                                                 \
    for (int ct = 0; ct < 4; ++ct) {                                                  \
        bf16x8 kf0 = *(const bf16x8*)&Kb[ct * 16 + lr][lg * 8];                       \
        bf16x8 kf1 = *(const bf16x8*)&Kb[ct * 16 + lr][32 + lg * 8];                  \
        f32x4 z; for (int r = 0; r < 4; ++r) z[r] = 0.f;                              \
        z = __builtin_amdgcn_mfma_f32_16x16x32_bf16(qf[0], kf0, z, 0, 0, 0);          \
        z = __builtin_amdgcn_mfma_f32_16x16x32_bf16(qf[1], kf1, z, 0, 0, 0);          \
        s[ct] = z;                                                                    \
    }                                                                                 \
    if ((tloc) + 1 < nt) {  /* prefetch next tile's mask */                           \
        const int t0n = t0 + BKV;                                                     \
        _Pragma("unroll")                                                             \
        for (int r = 0; r < 4; ++r) {                                                 \
            const float* mp = mb + (size_t)(4 * lg + r) * NSEQ + t0n + lr;            \
            _Pragma("unroll")                                                         \
            for (int ct = 0; ct < 4; ++ct) (MP)[r * 4 + ct] = mp[ct * 16];            \
        }                                                                             \
    }                                                                                 \
    _Pragma("unroll")                                                                 \
    for (int r = 0; r < 4; ++r)                                                       \
        for (int ct = 0; ct < 4; ++ct)                                                \
            s[ct][r] = fmaf((MU)[r * 4 + ct], MSC, s[ct][r]);                         \
    float mnew[4], sc[4], ps[4];                                                      \
    _Pragma("unroll")                                                                 \
    for (int r = 0; r < 4; ++r) {                                                     \
        float tm = fmaxf(fmaxf(s[0][r], s[1][r]), fmaxf(s[2][r], s[3][r]));           \
        tm = fmaxf(tm, __shfl_xor(tm, 1));                                            \
        tm = fmaxf(tm, __shfl_xor(tm, 2));                                            \
        tm = fmaxf(tm, __shfl_xor(tm, 4));                                            \
        tm = fmaxf(tm, __shfl_xor(tm, 8));                                            \
        mnew[r] = fmaxf(m_r[r], tm);                                                  \
        sc[r] = __builtin_amdgcn_exp2f(m_r[r] - mnew[r]);                             \
        ps[r] = 0.f;                                                                  \
    }                                                                                 \
    _Pragma("unroll")                                                                 \
    for (int ct = 0; ct < 4; ++ct) {                                                  \
        for (int r = 0; r < 4; ++r) {                                                 \
            float p = __builtin_amdgcn_exp2f(s[ct][r] - mnew[r]);                     \
            ps[r] += p;                                                               \
            Pl[wave][4 * lg + r][ct * 16 + lr] = f2bf(p);                             \
        }                                                                             \
    }                                                                                 \
    _Pragma("unroll")                                                                 \
    for (int r = 0; r < 4; ++r) {                                                     \
        float t = ps[r];                                                              \
        t += __shfl_xor(t, 1);                                                        \
        t += __shfl_xor(t, 2);                                                        \
        t += __shfl_xor(t, 4);                                                        \
        t += __shfl_xor(t, 8);                                                        \
        l_r[r] = l_r[r] * sc[r] + t;                                                  \
        m_r[r] = mnew[r];                                                             \
    }                                                                                 \
    _Pragma("unroll")                                                                 \
    for (int dt = 0; dt < 4; ++dt)                                                    \
        for (int r = 0; r < 4; ++r) acc[dt][r] *= sc[r];                              \
    bf16x8 pf0 = *(const bf16x8*)&Pl[wave][lr][lg * 8];                               \
    bf16x8 pf1 = *(const bf16x8*)&Pl[wave][lr][32 + lg * 8];                          \
    _Pragma("unroll")                                                                 \
    for (int dt = 0; dt < 4; ++dt) {                                                  \
        bf16x8 vf0 = *(const bf16x8*)&Vt[dt * 16 + lr][lg * 8];                       \
        bf16x8 vf1 = *(const bf16x8*)&Vt[dt * 16 + lr][32 + lg * 8];                  \
        acc[dt] = __builtin_amdgcn_mfma_f32_16x16x32_bf16(pf0, vf0, acc[dt], 0, 0, 0);\
        acc[dt] = __builtin_amdgcn_mfma_f32_16x16x32_bf16(pf1, vf1, acc[dt], 0, 0, 0);\
    }                                                                                 \
} while (0)

    for (int t = 0; t < nt; t += 2) {
        ATTN_STEP(mA, mB, t);
        ATTN_STEP(mB, mA, t + 1);
    }
#undef ATTN_STEP

    if (SPLIT == 1) {
        #pragma unroll
        for (int r = 0; r < 4; ++r) {
            float inv = 1.0f / l_r[r];
            int qrow = qt * BQ + wave * 16 + 4 * lg + r;
            float* op = out + ((size_t)b * NSEQ + qrow) * 128 + kk * 64;
            for (int dt = 0; dt < 4; ++dt) op[dt * 16 + lr] = acc[dt][r] * inv;
        }
    } else {
        float* pp = part + (size_t)((((b * 2 + kk) * 32 + qt) * SPLIT) + sp) * PART_STRIDE;
        #pragma unroll
        for (int r = 0; r < 4; ++r) {
            int prow = wave * 16 + 4 * lg + r;
            float* op = pp + prow * 64;
            for (int dt = 0; dt < 4; ++dt) op[dt * 16 + lr] = acc[dt][r];
            if (lr == 0) {
                pp[4096 + prow] = m_r[r];
                pp[4160 + prow] = l_r[r];
            }
        }
    }
}

// ---------------- combine partials ----------------
__global__ __launch_bounds__(256)
void combine_kernel(const float* __restrict__ part, float* __restrict__ out, int SPLIT) {
    const int qt = blockIdx.x, kk = blockIdx.y, b = blockIdx.z;
    const float* base = part + (size_t)(((b * 2 + kk) * 32 + qt) * SPLIT) * PART_STRIDE;
    const int row = threadIdx.x >> 2;
    const int c0 = (threadIdx.x & 3) << 4;

    float M = -INFINITY;
    for (int s = 0; s < SPLIT; ++s)
        M = fmaxf(M, base[(size_t)s * PART_STRIDE + 4096 + row]);

    float L = 0.f;
    float4 o[4];
    #pragma unroll
    for (int j = 0; j < 4; ++j) o[j] = make_float4(0.f, 0.f, 0.f, 0.f);

    for (int s = 0; s < SPLIT; ++s) {
        const float* pb = base + (size_t)s * PART_STRIDE;
        float w = exp2f(pb[4096 + row] - M);
        L += w * pb[4160 + row];
        const float4* ap = (const float4*)(pb + row * 64 + c0);
        #pragma unroll
        for (int j = 0; j < 4; ++j) {
            float4 a = ap[j];
            o[j].x += w * a.x; o[j].y += w * a.y;
            o[j].z += w * a.z; o[j].w += w * a.w;
        }
    }
    float inv = 1.0f / L;
    float* op = out + ((size_t)b * NSEQ + qt * 64 + row) * 128 + kk * 64 + c0;
    #pragma unroll
    for (int j = 0; j < 4; ++j) {
        float4 r = make_float4(o[j].x * inv, o[j].y * inv, o[j].z * inv, o[j].w * inv);
        ((float4*)op)[j] = r;
    }
}

extern "C" void kernel_launch(void* const* d_in, const int* in_sizes, int n_in,
                              void* d_out, int out_size, void* d_ws, size_t ws_size,
                              hipStream_t stream) {
    const float* q    = (const float*)d_in[0];
    const float* k    = (const float*)d_in[1];
    const float* v    = (const float*)d_in[2];
    const float* gi   = (const float*)d_in[3];
    const float* mask = (const float*)d_in[4];
    const float* Wg   = (const float*)d_in[5];
    const float* bg   = (const float*)d_in[6];
    float* out = (float*)d_out;

    float* wsA   = (float*)d_ws;            // 8*8*128 partial sums
    float* ws_sm = wsA + 8 * 8 * 128;       // 8*16 softmax
    int*   ws_idx = (int*)(ws_sm + 8 * NH); // 16 ints
    float* ws_part = (float*)((char*)d_ws + 65536);

    // choose KV-split from available scratch (host-side, deterministic)
    size_t need4 = (size_t)512 * 4 * PART_STRIDE * 4 + 65536;
    size_t need2 = (size_t)512 * 2 * PART_STRIDE * 4 + 65536;
    int SPLIT = (ws_size >= need4) ? 4 : (ws_size >= need2) ? 2 : 1;

    gate_partial<<<64, 256, 0, stream>>>(gi, wsA);
    gate_final<<<8, 256, 0, stream>>>(wsA, Wg, bg, ws_sm, ws_idx);
    lb_kernel<<<1, 64, 0, stream>>>(ws_sm, ws_idx, out + (size_t)8 * NSEQ * 128);

    dim3 grid(32 * SPLIT, 2, 8);
    attn_kernel<<<grid, 256, 0, stream>>>(q, k, v, mask, ws_idx, out, ws_part, SPLIT);
    if (SPLIT > 1) {
        dim3 cgrid(32, 2, 8);
        combine_kernel<<<cgrid, 256, 0, stream>>>(ws_part, out, SPLIT);
    }
}

// Round 3
// 160.388 us; speedup vs baseline: 2.0362x; 2.0362x over previous
//
#include <hip/hip_runtime.h>

#define NSEQ 2048
#define DH 64
#define NH 16
#define BQ 64
#define BKV 64
#define LP 72   // LDS row stride in bf16 elems (padded vs 64 to break bank conflicts)
#define PART_STRIDE 4224  // 64*64 acc + 64 m + 64 l floats per partial

typedef __attribute__((ext_vector_type(8))) short bf16x8;
typedef __attribute__((ext_vector_type(4))) float f32x4;

static __device__ __forceinline__ short f2bf(float f) {
    unsigned u = __float_as_uint(f);
    u += 0x7fffu + ((u >> 16) & 1u);   // round-to-nearest-even
    return (short)(u >> 16);
}

// ---------------- gating ----------------
__global__ void gate_partial(const float* __restrict__ gi, float* __restrict__ wsA) {
    int b = blockIdx.x >> 3, sl = blockIdx.x & 7;
    int tid = threadIdx.x;
    int g = tid & 127, half = tid >> 7;
    float s = 0.f;
    int n0 = sl * 256;
    for (int n = n0 + half; n < n0 + 256; n += 2)
        s += gi[((size_t)b * NSEQ + n) * 128 + g];
    __shared__ float part[2][128];
    part[half][g] = s;
    __syncthreads();
    if (tid < 128) wsA[(b * 8 + sl) * 128 + tid] = part[0][tid] + part[1][tid];
}

__global__ void gate_final(const float* __restrict__ wsA, const float* __restrict__ Wg,
                           const float* __restrict__ bg, float* __restrict__ ws_sm,
                           int* __restrict__ ws_idx) {
    int b = blockIdx.x, tid = threadIdx.x;
    __shared__ float meanv[128];
    __shared__ float logits[NH];
    if (tid < 128) {
        float s = 0.f;
        for (int sl = 0; sl < 8; ++sl) s += wsA[(b * 8 + sl) * 128 + tid];
        meanv[tid] = s * (1.0f / NSEQ);
    }
    __syncthreads();
    if (tid < 128) {
        int h = tid >> 3, j = tid & 7;
        float p = 0.f;
        for (int i = 0; i < 16; ++i) { int g = j + 8 * i; p += meanv[g] * Wg[h * 128 + g]; }
        p += __shfl_xor(p, 1);
        p += __shfl_xor(p, 2);
        p += __shfl_xor(p, 4);
        if (j == 0) logits[h] = p + bg[h];
    }
    __syncthreads();
    if (tid == 0) {
        float mx = logits[0];
        for (int h = 1; h < NH; ++h) mx = fmaxf(mx, logits[h]);
        float e[NH], sum = 0.f;
        for (int h = 0; h < NH; ++h) { e[h] = __expf(logits[h] - mx); sum += e[h]; }
        float inv = 1.0f / sum;
        for (int h = 0; h < NH; ++h) ws_sm[b * NH + h] = e[h] * inv;
        int i1 = 0;
        for (int h = 1; h < NH; ++h) if (logits[h] > logits[i1]) i1 = h;
        int i2 = (i1 == 0) ? 1 : 0;
        for (int h = 0; h < NH; ++h) if (h != i1 && logits[h] > logits[i2]) i2 = h;
        ws_idx[b * 2 + 0] = i1;
        ws_idx[b * 2 + 1] = i2;
    }
}

__global__ void lb_kernel(const float* __restrict__ ws_sm, const int* __restrict__ ws_idx,
                          float* __restrict__ out_lb) {
    if (threadIdx.x == 0 && blockIdx.x == 0) {
        float counts[NH];
        for (int h = 0; h < NH; ++h) counts[h] = 0.f;
        for (int i = 0; i < 16; ++i) counts[ws_idx[i]] += 1.0f;
        float lb = 0.f;
        for (int h = 0; h < NH; ++h) {
            float msm = 0.f;
            for (int b = 0; b < 8; ++b) msm += ws_sm[b * NH + h];
            msm *= (1.0f / 8.0f);
            lb += msm * (counts[h] / (16.0f + 1e-6f));
        }
        out_lb[0] = lb * (float)NH;
    }
}

// ---------------- attention (flash-decoding: KV split across blocks) ----------------
template<int SPLIT>
__global__ __launch_bounds__(256, 4)
void attn_kernel(const float* __restrict__ q, const float* __restrict__ k,
                 const float* __restrict__ v, const float* __restrict__ mask,
                 const int* __restrict__ topk, float* __restrict__ out,
                 float* __restrict__ part) {
    const int qt = blockIdx.x & 31;   // q-tile 0..31
    const int sp = blockIdx.x >> 5;   // kv-split index 0..SPLIT-1
    const int kk = blockIdx.y;        // 0..1
    const int b  = blockIdx.z;        // 0..7
    const int h  = topk[b * 2 + kk];
    const int tid = threadIdx.x;
    const int wave = tid >> 6;
    const int lane = tid & 63;
    const int lr = lane & 15;    // row-in-16 (A) / col (B, C/D)
    const int lg = lane >> 4;    // k-chunk group 0..3

    const int nt = 32 / SPLIT;            // KV tiles this block handles (compile-time)
    const int t_begin = sp * nt;          // first tile index

    __shared__ short Kb[BKV][LP];     // K tile, bf16 row-major [n][d]
    __shared__ short Vt[DH][LP];      // V tile transposed, [d][n]
    __shared__ short Pl[4][16][LP];   // per-wave P tile [qrow16][n64]

    const float QSC = 0.125f * 1.4426950408889634f; // 1/sqrt(64) * log2(e)
    const float MSC = 1.4426950408889634f;          // log2(e) for the mask add

    const size_t headoff = ((size_t)b * NH + h) * (size_t)NSEQ * DH;

    // Q fragments: lane holds q[row=lr][d = f*32 + lg*8 + j], scaled
    bf16x8 qf[2];
    {
        const float* qp = q + headoff + (size_t)(qt * BQ + wave * 16 + lr) * DH;
        #pragma unroll
        for (int f = 0; f < 2; ++f) {
            const float* p = qp + f * 32 + lg * 8;
            float4 a = *(const float4*)p;
            float4 c = *(const float4*)(p + 4);
            qf[f][0] = f2bf(a.x * QSC); qf[f][1] = f2bf(a.y * QSC);
            qf[f][2] = f2bf(a.z * QSC); qf[f][3] = f2bf(a.w * QSC);
            qf[f][4] = f2bf(c.x * QSC); qf[f][5] = f2bf(c.y * QSC);
            qf[f][6] = f2bf(c.z * QSC); qf[f][7] = f2bf(c.w * QSC);
        }
    }

    f32x4 acc[4];
    float m_r[4], l_r[4];
    #pragma unroll
    for (int dt = 0; dt < 4; ++dt)
        for (int r = 0; r < 4; ++r) acc[dt][r] = 0.f;
    #pragma unroll
    for (int r = 0; r < 4; ++r) { m_r[r] = -INFINITY; l_r[r] = 0.f; }

    const float* kb = k + headoff;
    const float* vb = v + headoff;
    const float* mb = mask + (size_t)b * NSEQ * NSEQ + (size_t)(qt * BQ + wave * 16) * NSEQ;

    const int srow = tid >> 4;        // staging row 0..15
    const int scol = (tid & 15) * 4;  // staging col 0,4..60

    for (int t = 0; t < nt; ++t) {
        const int t0 = (t_begin + t) * BKV;
        __syncthreads();  // previous iter's LDS reads done before overwrite
        #pragma unroll
        for (int pp = 0; pp < 4; ++pp) {
            int n = pp * 16 + srow;
            float4 k4 = *(const float4*)(kb + (size_t)(t0 + n) * DH + scol);
            *(short4*)&Kb[n][scol] = make_short4(f2bf(k4.x), f2bf(k4.y), f2bf(k4.z), f2bf(k4.w));
            float4 v4 = *(const float4*)(vb + (size_t)(t0 + n) * DH + scol);
            Vt[scol + 0][n] = f2bf(v4.x);
            Vt[scol + 1][n] = f2bf(v4.y);
            Vt[scol + 2][n] = f2bf(v4.z);
            Vt[scol + 3][n] = f2bf(v4.w);
        }
        __syncthreads();

        // S = (q/8*log2e) . K^T  -> per lane 4 col-tiles x 4 rows
        f32x4 s[4];
        #pragma unroll
        for (int ct = 0; ct < 4; ++ct) {
            bf16x8 kf0 = *(const bf16x8*)&Kb[ct * 16 + lr][lg * 8];
            bf16x8 kf1 = *(const bf16x8*)&Kb[ct * 16 + lr][32 + lg * 8];
            f32x4 z; for (int r = 0; r < 4; ++r) z[r] = 0.f;
            z = __builtin_amdgcn_mfma_f32_16x16x32_bf16(qf[0], kf0, z, 0, 0, 0);
            z = __builtin_amdgcn_mfma_f32_16x16x32_bf16(qf[1], kf1, z, 0, 0, 0);
            s[ct] = z;
        }
        // mask add (log2 domain): C/D layout row=4*lg+r, col=ct*16+lr
        #pragma unroll
        for (int r = 0; r < 4; ++r) {
            const float* mp = mb + (size_t)(4 * lg + r) * NSEQ + t0 + lr;
            #pragma unroll
            for (int ct = 0; ct < 4; ++ct)
                s[ct][r] = fmaf(mp[ct * 16], MSC, s[ct][r]);
        }
        // online softmax (log2 domain), row lives in one 16-lane group
        float mnew[4], sc[4], ps[4];
        #pragma unroll
        for (int r = 0; r < 4; ++r) {
            float tm = fmaxf(fmaxf(s[0][r], s[1][r]), fmaxf(s[2][r], s[3][r]));
            tm = fmaxf(tm, __shfl_xor(tm, 1));
            tm = fmaxf(tm, __shfl_xor(tm, 2));
            tm = fmaxf(tm, __shfl_xor(tm, 4));
            tm = fmaxf(tm, __shfl_xor(tm, 8));
            mnew[r] = fmaxf(m_r[r], tm);
            sc[r] = __builtin_amdgcn_exp2f(m_r[r] - mnew[r]);
            ps[r] = 0.f;
        }
        #pragma unroll
        for (int ct = 0; ct < 4; ++ct) {
            #pragma unroll
            for (int r = 0; r < 4; ++r) {
                float p = __builtin_amdgcn_exp2f(s[ct][r] - mnew[r]);
                ps[r] += p;
                Pl[wave][4 * lg + r][ct * 16 + lr] = f2bf(p);
            }
        }
        #pragma unroll
        for (int r = 0; r < 4; ++r) {
            float t2 = ps[r];
            t2 += __shfl_xor(t2, 1);
            t2 += __shfl_xor(t2, 2);
            t2 += __shfl_xor(t2, 4);
            t2 += __shfl_xor(t2, 8);
            l_r[r] = l_r[r] * sc[r] + t2;
            m_r[r] = mnew[r];
        }
        #pragma unroll
        for (int dt = 0; dt < 4; ++dt)
            for (int r = 0; r < 4; ++r) acc[dt][r] *= sc[r];

        // PV: A = P (same-wave LDS round trip, compiler orders via lgkmcnt)
        bf16x8 pf0 = *(const bf16x8*)&Pl[wave][lr][lg * 8];
        bf16x8 pf1 = *(const bf16x8*)&Pl[wave][lr][32 + lg * 8];
        #pragma unroll
        for (int dt = 0; dt < 4; ++dt) {
            bf16x8 vf0 = *(const bf16x8*)&Vt[dt * 16 + lr][lg * 8];
            bf16x8 vf1 = *(const bf16x8*)&Vt[dt * 16 + lr][32 + lg * 8];
            acc[dt] = __builtin_amdgcn_mfma_f32_16x16x32_bf16(pf0, vf0, acc[dt], 0, 0, 0);
            acc[dt] = __builtin_amdgcn_mfma_f32_16x16x32_bf16(pf1, vf1, acc[dt], 0, 0, 0);
        }
    }

    if (SPLIT == 1) {
        #pragma unroll
        for (int r = 0; r < 4; ++r) {
            float inv = 1.0f / l_r[r];
            int qrow = qt * BQ + wave * 16 + 4 * lg + r;
            float* op = out + ((size_t)b * NSEQ + qrow) * 128 + kk * 64;
            for (int dt = 0; dt < 4; ++dt) op[dt * 16 + lr] = acc[dt][r] * inv;
        }
    } else {
        float* pp = part + (size_t)((((b * 2 + kk) * 32 + qt) * SPLIT) + sp) * PART_STRIDE;
        #pragma unroll
        for (int r = 0; r < 4; ++r) {
            int prow = wave * 16 + 4 * lg + r;
            float* op = pp + prow * 64;
            for (int dt = 0; dt < 4; ++dt) op[dt * 16 + lr] = acc[dt][r];
            if (lr == 0) {
                pp[4096 + prow] = m_r[r];
                pp[4160 + prow] = l_r[r];
            }
        }
    }
}

// ---------------- combine partials ----------------
__global__ __launch_bounds__(256)
void combine_kernel(const float* __restrict__ part, float* __restrict__ out, int SPLIT) {
    const int qt = blockIdx.x, kk = blockIdx.y, b = blockIdx.z;
    const float* base = part + (size_t)(((b * 2 + kk) * 32 + qt) * SPLIT) * PART_STRIDE;
    const int row = threadIdx.x >> 2;
    const int c0 = (threadIdx.x & 3) << 4;

    float M = -INFINITY;
    for (int s = 0; s < SPLIT; ++s)
        M = fmaxf(M, base[(size_t)s * PART_STRIDE + 4096 + row]);

    float L = 0.f;
    float4 o[4];
    #pragma unroll
    for (int j = 0; j < 4; ++j) o[j] = make_float4(0.f, 0.f, 0.f, 0.f);

    for (int s = 0; s < SPLIT; ++s) {
        const float* pb = base + (size_t)s * PART_STRIDE;
        float w = exp2f(pb[4096 + row] - M);
        L += w * pb[4160 + row];
        const float4* ap = (const float4*)(pb + row * 64 + c0);
        #pragma unroll
        for (int j = 0; j < 4; ++j) {
            float4 a = ap[j];
            o[j].x += w * a.x; o[j].y += w * a.y;
            o[j].z += w * a.z; o[j].w += w * a.w;
        }
    }
    float inv = 1.0f / L;
    float* op = out + ((size_t)b * NSEQ + qt * 64 + row) * 128 + kk * 64 + c0;
    #pragma unroll
    for (int j = 0; j < 4; ++j) {
        float4 r = make_float4(o[j].x * inv, o[j].y * inv, o[j].z * inv, o[j].w * inv);
        ((float4*)op)[j] = r;
    }
}

extern "C" void kernel_launch(void* const* d_in, const int* in_sizes, int n_in,
                              void* d_out, int out_size, void* d_ws, size_t ws_size,
                              hipStream_t stream) {
    const float* q    = (const float*)d_in[0];
    const float* k    = (const float*)d_in[1];
    const float* v    = (const float*)d_in[2];
    const float* gi   = (const float*)d_in[3];
    const float* mask = (const float*)d_in[4];
    const float* Wg   = (const float*)d_in[5];
    const float* bg   = (const float*)d_in[6];
    float* out = (float*)d_out;

    float* wsA   = (float*)d_ws;            // 8*8*128 partial sums
    float* ws_sm = wsA + 8 * 8 * 128;       // 8*16 softmax
    int*   ws_idx = (int*)(ws_sm + 8 * NH); // 16 ints
    float* ws_part = (float*)((char*)d_ws + 65536);

    // choose KV-split from available scratch (host-side, deterministic)
    size_t need4 = (size_t)512 * 4 * PART_STRIDE * 4 + 65536;
    int SPLIT = (ws_size >= need4) ? 4 : 1;

    gate_partial<<<64, 256, 0, stream>>>(gi, wsA);
    gate_final<<<8, 256, 0, stream>>>(wsA, Wg, bg, ws_sm, ws_idx);
    lb_kernel<<<1, 64, 0, stream>>>(ws_sm, ws_idx, out + (size_t)8 * NSEQ * 128);

    dim3 grid(32 * SPLIT, 2, 8);
    if (SPLIT == 4) {
        attn_kernel<4><<<grid, 256, 0, stream>>>(q, k, v, mask, ws_idx, out, ws_part);
        dim3 cgrid(32, 2, 8);
        combine_kernel<<<cgrid, 256, 0, stream>>>(ws_part, out, SPLIT);
    } else {
        attn_kernel<1><<<grid, 256, 0, stream>>>(q, k, v, mask, ws_idx, out, ws_part);
    }
}

// Round 4
// 114.911 us; speedup vs baseline: 2.8421x; 1.3958x over previous
//
#include <hip/hip_runtime.h>

#define NSEQ 2048
#define DH 64
#define NH 16
#define BQ 64
#define BKV 64
#define KP 72   // K LDS row stride (bf16): 144B -> b128 reads 16B-aligned, 2-way (free)
#define VP 68   // V/P LDS row stride: 136B -> 8B-aligned b64, reduced write conflicts
#define PART_STRIDE 4224  // 64*64 acc + 64 m + 64 l floats per partial

typedef __attribute__((ext_vector_type(8))) short bf16x8;
typedef __attribute__((ext_vector_type(4))) short s16x4;
typedef __attribute__((ext_vector_type(4))) float f32x4;

static __device__ __forceinline__ short f2bf(float f) {
    __bf16 b = (__bf16)f;              // HW cvt (RNE); pairs fuse to v_cvt_pk_bf16_f32
    return __builtin_bit_cast(short, b);
}

// ---------------- gating ----------------
__global__ void gate_partial(const float* __restrict__ gi, float* __restrict__ wsA, int SL) {
    int b = blockIdx.x / SL, sl = blockIdx.x % SL;
    int rows = NSEQ / SL;
    int tid = threadIdx.x;
    int g = tid & 127, half = tid >> 7;
    float s = 0.f;
    int n0 = sl * rows;
    for (int n = n0 + half; n < n0 + rows; n += 2)
        s += gi[((size_t)b * NSEQ + n) * 128 + g];
    __shared__ float part[2][128];
    part[half][g] = s;
    __syncthreads();
    if (tid < 128) wsA[(b * SL + sl) * 128 + tid] = part[0][tid] + part[1][tid];
}

__global__ void gate_final(const float* __restrict__ wsA, const float* __restrict__ Wg,
                           const float* __restrict__ bg, float* __restrict__ ws_sm,
                           int* __restrict__ ws_idx, int SL) {
    int b = blockIdx.x, tid = threadIdx.x;
    __shared__ float meanv[128];
    __shared__ float logits[NH];
    if (tid < 128) {
        float s = 0.f;
        for (int sl = 0; sl < SL; ++sl) s += wsA[(b * SL + sl) * 128 + tid];
        meanv[tid] = s * (1.0f / NSEQ);
    }
    __syncthreads();
    if (tid < 128) {
        int h = tid >> 3, j = tid & 7;
        float p = 0.f;
        for (int i = 0; i < 16; ++i) { int g = j + 8 * i; p += meanv[g] * Wg[h * 128 + g]; }
        p += __shfl_xor(p, 1);
        p += __shfl_xor(p, 2);
        p += __shfl_xor(p, 4);
        if (j == 0) logits[h] = p + bg[h];
    }
    __syncthreads();
    if (tid == 0) {
        float mx = logits[0];
        for (int h = 1; h < NH; ++h) mx = fmaxf(mx, logits[h]);
        float e[NH], sum = 0.f;
        for (int h = 0; h < NH; ++h) { e[h] = __expf(logits[h] - mx); sum += e[h]; }
        float inv = 1.0f / sum;
        for (int h = 0; h < NH; ++h) ws_sm[b * NH + h] = e[h] * inv;
        int i1 = 0;
        for (int h = 1; h < NH; ++h) if (logits[h] > logits[i1]) i1 = h;
        int i2 = (i1 == 0) ? 1 : 0;
        for (int h = 0; h < NH; ++h) if (h != i1 && logits[h] > logits[i2]) i2 = h;
        ws_idx[b * 2 + 0] = i1;
        ws_idx[b * 2 + 1] = i2;
    }
}

__global__ void lb_kernel(const float* __restrict__ ws_sm, const int* __restrict__ ws_idx,
                          float* __restrict__ out_lb) {
    if (threadIdx.x == 0 && blockIdx.x == 0) {
        float counts[NH];
        for (int h = 0; h < NH; ++h) counts[h] = 0.f;
        for (int i = 0; i < 16; ++i) counts[ws_idx[i]] += 1.0f;
        float lb = 0.f;
        for (int h = 0; h < NH; ++h) {
            float msm = 0.f;
            for (int b = 0; b < 8; ++b) msm += ws_sm[b * NH + h];
            msm *= (1.0f / 8.0f);
            lb += msm * (counts[h] / (16.0f + 1e-6f));
        }
        out_lb[0] = lb * (float)NH;
    }
}

// ---------------- attention (flash-decoding: KV split across blocks) ----------------
template<int SPLIT>
__global__ __launch_bounds__(256, 4)
void attn_kernel(const float* __restrict__ q, const float* __restrict__ k,
                 const float* __restrict__ v, const float* __restrict__ mask,
                 const int* __restrict__ topk, float* __restrict__ out,
                 float* __restrict__ part) {
    const int qt = blockIdx.x & 31;   // q-tile 0..31
    const int sp = blockIdx.x >> 5;   // kv-split index 0..SPLIT-1
    const int kk = blockIdx.y;        // 0..1
    const int b  = blockIdx.z;        // 0..7
    const int h  = topk[b * 2 + kk];
    const int tid = threadIdx.x;
    const int wave = tid >> 6;
    const int lane = tid & 63;
    const int lr = lane & 15;    // row-in-16 (A) / col (B, C/D)
    const int lg = lane >> 4;    // k-chunk group 0..3

    const int nt = 32 / SPLIT;
    const int t_begin = sp * nt;

    __shared__ short Kb[BKV][KP];     // K tile, bf16 row-major [n][d]      9216 B
    __shared__ short Vt[DH][VP];      // V tile transposed, [d][n]          8704 B
    __shared__ short Pl[4][16][VP];   // per-wave P tile [qrow16][n64]      8704 B

    const float QSC = 0.125f * 1.4426950408889634f; // 1/sqrt(64) * log2(e)
    const float MSC = 1.4426950408889634f;          // log2(e) for the mask add

    const size_t headoff = ((size_t)b * NH + h) * (size_t)NSEQ * DH;

    // Q fragments: lane holds q[row=lr][d = f*32 + lg*8 + j], scaled
    bf16x8 qf[2];
    {
        const float* qp = q + headoff + (size_t)(qt * BQ + wave * 16 + lr) * DH;
        #pragma unroll
        for (int f = 0; f < 2; ++f) {
            const float* p = qp + f * 32 + lg * 8;
            float4 a = *(const float4*)p;
            float4 c = *(const float4*)(p + 4);
            qf[f][0] = f2bf(a.x * QSC); qf[f][1] = f2bf(a.y * QSC);
            qf[f][2] = f2bf(a.z * QSC); qf[f][3] = f2bf(a.w * QSC);
            qf[f][4] = f2bf(c.x * QSC); qf[f][5] = f2bf(c.y * QSC);
            qf[f][6] = f2bf(c.z * QSC); qf[f][7] = f2bf(c.w * QSC);
        }
    }

    f32x4 acc[4];
    float m_r[4], l_r[4];
    #pragma unroll
    for (int dt = 0; dt < 4; ++dt)
        for (int r = 0; r < 4; ++r) acc[dt][r] = 0.f;
    #pragma unroll
    for (int r = 0; r < 4; ++r) { m_r[r] = -INFINITY; l_r[r] = 0.f; }

    const float* kb = k + headoff;
    const float* vb = v + headoff;
    const float* mb = mask + (size_t)b * NSEQ * NSEQ + (size_t)(qt * BQ + wave * 16) * NSEQ;

    const int srow = tid >> 4;        // staging row 0..15
    const int scol = (tid & 15) * 4;  // staging col 0,4..60

    float4 kreg[4], vreg[4];
    float  mreg[16];

    auto issue_kv = [&](int t0) {
        #pragma unroll
        for (int pp = 0; pp < 4; ++pp) {
            int n = t0 + pp * 16 + srow;
            kreg[pp] = *(const float4*)(kb + (size_t)n * DH + scol);
            vreg[pp] = *(const float4*)(vb + (size_t)n * DH + scol);
        }
    };
    auto issue_mask = [&](int t0) {
        #pragma unroll
        for (int r = 0; r < 4; ++r) {
            const float* mp = mb + (size_t)(4 * lg + r) * NSEQ + t0 + lr;
            #pragma unroll
            for (int ct = 0; ct < 4; ++ct) mreg[r * 4 + ct] = mp[ct * 16];
        }
    };

    issue_kv(t_begin * BKV);
    issue_mask(t_begin * BKV);

    for (int t = 0; t < nt; ++t) {
        const int t0 = (t_begin + t) * BKV;
        __syncthreads();  // previous iter's LDS reads done before overwrite
        #pragma unroll
        for (int pp = 0; pp < 4; ++pp) {
            int n = pp * 16 + srow;
            s16x4 sk = { f2bf(kreg[pp].x), f2bf(kreg[pp].y), f2bf(kreg[pp].z), f2bf(kreg[pp].w) };
            *(s16x4*)&Kb[n][scol] = sk;
            Vt[scol + 0][n] = f2bf(vreg[pp].x);
            Vt[scol + 1][n] = f2bf(vreg[pp].y);
            Vt[scol + 2][n] = f2bf(vreg[pp].z);
            Vt[scol + 3][n] = f2bf(vreg[pp].w);
        }
        __syncthreads();

        // S = (q/8*log2e) . K^T
        f32x4 s[4];
        #pragma unroll
        for (int ct = 0; ct < 4; ++ct) {
            bf16x8 kf0 = *(const bf16x8*)&Kb[ct * 16 + lr][lg * 8];
            bf16x8 kf1 = *(const bf16x8*)&Kb[ct * 16 + lr][32 + lg * 8];
            f32x4 z; for (int r = 0; r < 4; ++r) z[r] = 0.f;
            z = __builtin_amdgcn_mfma_f32_16x16x32_bf16(qf[0], kf0, z, 0, 0, 0);
            z = __builtin_amdgcn_mfma_f32_16x16x32_bf16(qf[1], kf1, z, 0, 0, 0);
            s[ct] = z;
        }
        // mask add (log2 domain): C/D layout row=4*lg+r, col=ct*16+lr
        #pragma unroll
        for (int r = 0; r < 4; ++r)
            #pragma unroll
            for (int ct = 0; ct < 4; ++ct)
                s[ct][r] = fmaf(mreg[r * 4 + ct], MSC, s[ct][r]);

        // prefetch next tile (regs just freed; loads in flight across softmax+PV)
        if (t + 1 < nt) { issue_kv(t0 + BKV); issue_mask(t0 + BKV); }

        // online softmax (log2 domain)
        float mnew[4], sc[4], ps[4];
        #pragma unroll
        for (int r = 0; r < 4; ++r) {
            float tm = fmaxf(fmaxf(s[0][r], s[1][r]), fmaxf(s[2][r], s[3][r]));
            tm = fmaxf(tm, __shfl_xor(tm, 1));
            tm = fmaxf(tm, __shfl_xor(tm, 2));
            tm = fmaxf(tm, __shfl_xor(tm, 4));
            tm = fmaxf(tm, __shfl_xor(tm, 8));
            mnew[r] = fmaxf(m_r[r], tm);
            sc[r] = __builtin_amdgcn_exp2f(m_r[r] - mnew[r]);
            ps[r] = 0.f;
        }
        #pragma unroll
        for (int ct = 0; ct < 4; ++ct) {
            #pragma unroll
            for (int r = 0; r < 4; ++r) {
                float p = __builtin_amdgcn_exp2f(s[ct][r] - mnew[r]);
                ps[r] += p;
                Pl[wave][4 * lg + r][ct * 16 + lr] = f2bf(p);  // stride-68 rows: conflict-free
            }
        }
        #pragma unroll
        for (int r = 0; r < 4; ++r) {
            float t2 = ps[r];
            t2 += __shfl_xor(t2, 1);
            t2 += __shfl_xor(t2, 2);
            t2 += __shfl_xor(t2, 4);
            t2 += __shfl_xor(t2, 8);
            l_r[r] = l_r[r] * sc[r] + t2;
            m_r[r] = mnew[r];
        }
        #pragma unroll
        for (int dt = 0; dt < 4; ++dt)
            for (int r = 0; r < 4; ++r) acc[dt][r] *= sc[r];

        // PV: A = P (same-wave LDS round trip; 2xb64 reads, 8B aligned)
        s16x4 p00 = *(const s16x4*)&Pl[wave][lr][lg * 8];
        s16x4 p01 = *(const s16x4*)&Pl[wave][lr][lg * 8 + 4];
        s16x4 p10 = *(const s16x4*)&Pl[wave][lr][32 + lg * 8];
        s16x4 p11 = *(const s16x4*)&Pl[wave][lr][32 + lg * 8 + 4];
        bf16x8 pf0 = __builtin_shufflevector(p00, p01, 0, 1, 2, 3, 4, 5, 6, 7);
        bf16x8 pf1 = __builtin_shufflevector(p10, p11, 0, 1, 2, 3, 4, 5, 6, 7);
        #pragma unroll
        for (int dt = 0; dt < 4; ++dt) {
            s16x4 v00 = *(const s16x4*)&Vt[dt * 16 + lr][lg * 8];
            s16x4 v01 = *(const s16x4*)&Vt[dt * 16 + lr][lg * 8 + 4];
            s16x4 v10 = *(const s16x4*)&Vt[dt * 16 + lr][32 + lg * 8];
            s16x4 v11 = *(const s16x4*)&Vt[dt * 16 + lr][32 + lg * 8 + 4];
            bf16x8 vf0 = __builtin_shufflevector(v00, v01, 0, 1, 2, 3, 4, 5, 6, 7);
            bf16x8 vf1 = __builtin_shufflevector(v10, v11, 0, 1, 2, 3, 4, 5, 6, 7);
            acc[dt] = __builtin_amdgcn_mfma_f32_16x16x32_bf16(pf0, vf0, acc[dt], 0, 0, 0);
            acc[dt] = __builtin_amdgcn_mfma_f32_16x16x32_bf16(pf1, vf1, acc[dt], 0, 0, 0);
        }
    }

    if (SPLIT == 1) {
        #pragma unroll
        for (int r = 0; r < 4; ++r) {
            float inv = 1.0f / l_r[r];
            int qrow = qt * BQ + wave * 16 + 4 * lg + r;
            float* op = out + ((size_t)b * NSEQ + qrow) * 128 + kk * 64;
            for (int dt = 0; dt < 4; ++dt) op[dt * 16 + lr] = acc[dt][r] * inv;
        }
    } else {
        float* pp = part + (size_t)((((b * 2 + kk) * 32 + qt) * SPLIT) + sp) * PART_STRIDE;
        #pragma unroll
        for (int r = 0; r < 4; ++r) {
            int prow = wave * 16 + 4 * lg + r;
            float* op = pp + prow * 64;
            for (int dt = 0; dt < 4; ++dt) op[dt * 16 + lr] = acc[dt][r];
            if (lr == 0) {
                pp[4096 + prow] = m_r[r];
                pp[4160 + prow] = l_r[r];
            }
        }
    }
}

// ---------------- combine partials ----------------
__global__ __launch_bounds__(256)
void combine_kernel(const float* __restrict__ part, float* __restrict__ out, int SPLIT) {
    const int qt = blockIdx.x, kk = blockIdx.y, b = blockIdx.z;
    const float* base = part + (size_t)(((b * 2 + kk) * 32 + qt) * SPLIT) * PART_STRIDE;
    const int row = threadIdx.x >> 2;
    const int c0 = (threadIdx.x & 3) << 4;

    float M = -INFINITY;
    for (int s = 0; s < SPLIT; ++s)
        M = fmaxf(M, base[(size_t)s * PART_STRIDE + 4096 + row]);

    float L = 0.f;
    float4 o[4];
    #pragma unroll
    for (int j = 0; j < 4; ++j) o[j] = make_float4(0.f, 0.f, 0.f, 0.f);

    for (int s = 0; s < SPLIT; ++s) {
        const float* pb = base + (size_t)s * PART_STRIDE;
        float w = exp2f(pb[4096 + row] - M);
        L += w * pb[4160 + row];
        const float4* ap = (const float4*)(pb + row * 64 + c0);
        #pragma unroll
        for (int j = 0; j < 4; ++j) {
            float4 a = ap[j];
            o[j].x += w * a.x; o[j].y += w * a.y;
            o[j].z += w * a.z; o[j].w += w * a.w;
        }
    }
    float inv = 1.0f / L;
    float* op = out + ((size_t)b * NSEQ + qt * 64 + row) * 128 + kk * 64 + c0;
    #pragma unroll
    for (int j = 0; j < 4; ++j) {
        float4 r = make_float4(o[j].x * inv, o[j].y * inv, o[j].z * inv, o[j].w * inv);
        ((float4*)op)[j] = r;
    }
}

extern "C" void kernel_launch(void* const* d_in, const int* in_sizes, int n_in,
                              void* d_out, int out_size, void* d_ws, size_t ws_size,
                              hipStream_t stream) {
    const float* q    = (const float*)d_in[0];
    const float* k    = (const float*)d_in[1];
    const float* v    = (const float*)d_in[2];
    const float* gi   = (const float*)d_in[3];
    const float* mask = (const float*)d_in[4];
    const float* Wg   = (const float*)d_in[5];
    const float* bg   = (const float*)d_in[6];
    float* out = (float*)d_out;

    const size_t part_bytes = (size_t)512 * 4 * PART_STRIDE * 4;  // 34,603,008
    const size_t needA = part_bytes + (size_t)8 * 64 * 128 * 4 + 4096;  // big layout
    const size_t needB = 65536 + part_bytes;                            // round-3 layout

    int SL, SPLIT;
    float* ws_part;
    float* wsA;
    if (ws_size >= needA) {
        SL = 64; SPLIT = 4;
        ws_part = (float*)d_ws;                          // partials first
        wsA = (float*)((char*)d_ws + part_bytes);        // gating scratch after
    } else if (ws_size >= needB) {
        SL = 8; SPLIT = 4;
        wsA = (float*)d_ws;
        ws_part = (float*)((char*)d_ws + 65536);
    } else {
        SL = 8; SPLIT = 1;
        wsA = (float*)d_ws;
        ws_part = (float*)d_ws;
    }
    float* ws_sm = wsA + 8 * SL * 128;
    int*   ws_idx = (int*)(ws_sm + 8 * NH);

    gate_partial<<<8 * SL, 256, 0, stream>>>(gi, wsA, SL);
    gate_final<<<8, 256, 0, stream>>>(wsA, Wg, bg, ws_sm, ws_idx, SL);
    lb_kernel<<<1, 64, 0, stream>>>(ws_sm, ws_idx, out + (size_t)8 * NSEQ * 128);

    dim3 grid(32 * SPLIT, 2, 8);
    if (SPLIT == 4) {
        attn_kernel<4><<<grid, 256, 0, stream>>>(q, k, v, mask, ws_idx, out, ws_part);
        dim3 cgrid(32, 2, 8);
        combine_kernel<<<cgrid, 256, 0, stream>>>(ws_part, out, SPLIT);
    } else {
        attn_kernel<1><<<grid, 256, 0, stream>>>(q, k, v, mask, ws_idx, out, ws_part);
    }
}